// Round 6
// baseline (249.825 us; speedup 1.0000x reference)
//
#include <hip/hip_runtime.h>

// GraphAttention fused forward for MI355X (gfx950), MFMA + software-pipelined attn.
// B=4, N=2048, F=64, FP=32, H=4.  Output: [B,N,H*FP] f32 ++ uloss ++ eloss.

#define B_ 4
#define N_ 2048
#define F_ 64
#define FP_ 32
#define H_ 4
#define C_ 128
#define IT_ 16                 // i-rows per attn block
#define ITILES_ (N_ / IT_)     // 128
#define JCA_ 8                 // j-chunks (partial accumulation, occupancy)
#define JSPANA_ (N_ / JCA_)    // 256
#define KC_ (JSPANA_ / 32)     // 8 MFMA k-steps per wave

typedef __attribute__((ext_vector_type(8))) short short8v;   // 8 bf16 = 4 VGPRs
typedef __attribute__((ext_vector_type(4))) float f32x4;     // MFMA C/D

__device__ __forceinline__ unsigned short f2bf(float f) {    // RNE fp32->bf16
    unsigned u = __float_as_uint(f);
    u += 0x7fffu + ((u >> 16) & 1u);
    return (unsigned short)(u >> 16);
}

// ---------------------------------------------------------------- kernel 1
// feats = x@W per head via MFMA; writes featsT bf16 [b][h][d][n] + s,t fp32.
// Block = (b, 64-row n-tile); 4 waves = 4 heads.
__global__ __launch_bounds__(256) void prep_kernel(
    const float* __restrict__ x, const float* __restrict__ W,
    const float* __restrict__ a_self, const float* __restrict__ a_neigh,
    unsigned short* __restrict__ featsT, float* __restrict__ sbuf,
    float* __restrict__ tbuf)
{
    int blk = blockIdx.x;              // b*32 + nt
    int b = blk >> 5, nt = blk & 31;
    int n0 = nt << 6;
    int t = threadIdx.x, h = t >> 6, lane = t & 63;
    int quad = lane >> 4, col = lane & 15;

    // B-frags: W[h][f][d] bf16; k=f packed as quad*8+e (same mapping as A)
    short8v bw[2][2];
    const float* Wh = W + (size_t)h * F_ * FP_;
#pragma unroll
    for (int kc = 0; kc < 2; ++kc)
#pragma unroll
        for (int dt = 0; dt < 2; ++dt)
#pragma unroll
            for (int e = 0; e < 8; ++e) {
                int f = kc * 32 + quad * 8 + e;
                bw[kc][dt][e] = (short)f2bf(Wh[f * FP_ + dt * 16 + col]);
            }
    float as0 = a_self[h * FP_ + col],  as1 = a_self[h * FP_ + 16 + col];
    float an0 = a_neigh[h * FP_ + col], an1 = a_neigh[h * FP_ + 16 + col];
    size_t hrow = ((size_t)b * H_ + h) * N_;
    size_t ftb  = ((size_t)b * H_ + h) * FP_;

    for (int ms = 0; ms < 4; ++ms) {
        int row = n0 + ms * 16 + col;          // A row m = lane&15
        const float* xr = x + ((size_t)b * N_ + row) * F_;
        f32x4 acc0 = {0.f, 0.f, 0.f, 0.f}, acc1 = {0.f, 0.f, 0.f, 0.f};
#pragma unroll
        for (int kc = 0; kc < 2; ++kc) {
            float4 x0 = *(const float4*)(xr + kc * 32 + quad * 8);
            float4 x1 = *(const float4*)(xr + kc * 32 + quad * 8 + 4);
            short8v av;
            av[0] = (short)f2bf(x0.x); av[1] = (short)f2bf(x0.y);
            av[2] = (short)f2bf(x0.z); av[3] = (short)f2bf(x0.w);
            av[4] = (short)f2bf(x1.x); av[5] = (short)f2bf(x1.y);
            av[6] = (short)f2bf(x1.z); av[7] = (short)f2bf(x1.w);
            acc0 = __builtin_amdgcn_mfma_f32_16x16x32_bf16(av, bw[kc][0], acc0, 0, 0, 0);
            acc1 = __builtin_amdgcn_mfma_f32_16x16x32_bf16(av, bw[kc][1], acc1, 0, 0, 0);
        }
        // C layout: row = quad*4+rr, col = lane&15 (verified m89/m91)
        {
            ushort4 v0, v1;
            v0.x = f2bf(acc0[0]); v0.y = f2bf(acc0[1]);
            v0.z = f2bf(acc0[2]); v0.w = f2bf(acc0[3]);
            v1.x = f2bf(acc1[0]); v1.y = f2bf(acc1[1]);
            v1.z = f2bf(acc1[2]); v1.w = f2bf(acc1[3]);
            size_t nidx = (size_t)n0 + ms * 16 + quad * 4;
            *(ushort4*)(featsT + (ftb + col) * N_ + nidx)      = v0;
            *(ushort4*)(featsT + (ftb + 16 + col) * N_ + nidx) = v1;
        }
#pragma unroll
        for (int rr = 0; rr < 4; ++rr) {
            float sv = acc0[rr] * as0 + acc1[rr] * as1;
            float tv = acc0[rr] * an0 + acc1[rr] * an1;
#pragma unroll
            for (int off = 8; off; off >>= 1) {
                sv += __shfl_down(sv, off);
                tv += __shfl_down(tv, off);
            }
            if (col == 0) {
                int n = n0 + ms * 16 + quad * 4 + rr;
                sbuf[hrow + n] = sv;
                tbuf[hrow + n] = tv;
            }
        }
    }
}

// ---------------------------------------------------------------- kernel 2
// Block = (b, 16-row i-tile, jc); 4 waves = 4 heads. No LDS, no barriers.
// Depth-1 software pipeline: prefetch kc+1's 8 vectors while computing kc.
// P built in-register in MFMA A-layout, PV via mfma 16x16x32 bf16.
__global__ __launch_bounds__(256, 4) void attn_kernel(
    const float* __restrict__ adj, const float* __restrict__ msk,
    const unsigned short* __restrict__ featsT,
    const float* __restrict__ sbuf, const float* __restrict__ tbuf,
    float* __restrict__ part, float* __restrict__ lpart)
{
    int blk = blockIdx.x;
    int jc = blk & (JCA_ - 1);
    int it = (blk >> 3) & (ITILES_ - 1);
    int b  = blk >> 10;
    int t = threadIdx.x, h = t >> 6, lane = t & 63;
    int quad = lane >> 4, r = lane & 15;
    int i0 = it * IT_;
    int jbase = jc * JSPANA_;

    size_t hrow = ((size_t)b * H_ + h) * N_;
    float si = sbuf[hrow + i0 + r];
    const float* trow = tbuf + hrow + jbase + quad * 8;
    const unsigned short* ft0 = featsT + (((size_t)b * H_ + h) * FP_ + r) * N_
                                + jbase + quad * 8;
    const unsigned short* ft1 = ft0 + (size_t)16 * N_;
    const float* adjb = adj + ((size_t)b * N_ + i0 + r) * N_ + jbase + quad * 8;
    const float* mskb = msk + ((size_t)b * N_ + i0 + r) * N_ + jbase + quad * 8;

    f32x4 acc0 = {0.f, 0.f, 0.f, 0.f}, acc1 = {0.f, 0.f, 0.f, 0.f};
    float l = 0.f, A = 0.f, nz = 0.f;

    // pipeline stage registers (current)
    float4 a0 = *(const float4*)(adjb);
    float4 a1 = *(const float4*)(adjb + 4);
    float4 m0 = *(const float4*)(mskb);
    float4 m1 = *(const float4*)(mskb + 4);
    float4 t0 = *(const float4*)(trow);
    float4 t1 = *(const float4*)(trow + 4);
    short8v bv0 = *(const short8v*)(ft0);
    short8v bv1 = *(const short8v*)(ft1);

#pragma unroll
    for (int kc = 0; kc < KC_; ++kc) {
        int kn = (kc < KC_ - 1) ? (kc + 1) * 32 : kc * 32;   // clamped prefetch
        float4 na0 = *(const float4*)(adjb + kn);
        float4 na1 = *(const float4*)(adjb + kn + 4);
        float4 nm0 = *(const float4*)(mskb + kn);
        float4 nm1 = *(const float4*)(mskb + kn + 4);
        float4 nt0 = *(const float4*)(trow + kn);
        float4 nt1 = *(const float4*)(trow + kn + 4);
        short8v nb0 = *(const short8v*)(ft0 + kn);
        short8v nb1 = *(const short8v*)(ft1 + kn);

        float av[8] = {a0.x, a0.y, a0.z, a0.w, a1.x, a1.y, a1.z, a1.w};
        float mv[8] = {m0.x, m0.y, m0.z, m0.w, m1.x, m1.y, m1.z, m1.w};
        float tv[8] = {t0.x, t0.y, t0.z, t0.w, t1.x, t1.y, t1.z, t1.w};
        short8v ap;
#pragma unroll
        for (int q = 0; q < 8; ++q) {
            float dv = si + tv[q];
            dv = fmaxf(dv, 0.2f * dv);            // LeakyReLU(0.2)
            dv += mv[q];
            float e = __expf(dv);                 // bounded: no max-subtract
            float p = e * av[q];
            l += e; A += p;
            nz += (av[q] == 0.f ? 1.f : 0.f) - (p == 0.f ? 1.f : 0.f);
            ap[q] = (short)f2bf(p);
        }
        acc0 = __builtin_amdgcn_mfma_f32_16x16x32_bf16(ap, bv0, acc0, 0, 0, 0);
        acc1 = __builtin_amdgcn_mfma_f32_16x16x32_bf16(ap, bv1, acc1, 0, 0, 0);

        a0 = na0; a1 = na1; m0 = nm0; m1 = nm1;
        t0 = nt0; t1 = nt1; bv0 = nb0; bv1 = nb1;
    }
    // row totals live in lanes 0-15 after folding the 4 k-group lanes
    l  += __shfl_down(l, 32);  l  += __shfl_down(l, 16);
    A  += __shfl_down(A, 32);  A  += __shfl_down(A, 16);
    nz += __shfl_down(nz, 32); nz += __shfl_down(nz, 16);

    size_t pb = ((((size_t)(b * H_ + h) * ITILES_ + it) * JCA_ + jc) * 2) * 256;
    *(f32x4*)&part[pb + lane * 4]       = acc0;   // raw C-frag, coalesced
    *(f32x4*)&part[pb + 256 + lane * 4] = acc1;
    if (lane < 16) {
        size_t lb = (((size_t)(b * H_ + h) * ITILES_ + it) * JCA_ + jc) * 48;
        lpart[lb + lane]      = l;
        lpart[lb + 16 + lane] = A;
        lpart[lb + 32 + lane] = nz;
    }
}

// ---------------------------------------------------------------- kernel 3
// Block = (b, i-tile). Merge jc partials (raw C-frag layout), /l, bias, BN,
// ReLU, LDS transpose, coalesced out; per-(block,h) loss partials.
__global__ __launch_bounds__(256) void final_kernel(
    const float* __restrict__ part, const float* __restrict__ lpart,
    const float* __restrict__ bias, const float* __restrict__ gamma,
    const float* __restrict__ beta, const float* __restrict__ mmean,
    const float* __restrict__ mvar, float2* __restrict__ lossbuf,
    float* __restrict__ out)
{
    __shared__ float ldsl[H_ * 16];
    __shared__ float ldso[IT_ * 132];
    int blk = blockIdx.x;              // b*128 + it
    int b = blk >> 7, it = blk & 127;
    int t = threadIdx.x, h = t >> 6, lane = t & 63;
    int quad = lane >> 4, col = lane & 15;

    size_t pb = (((size_t)(b * H_ + h) * ITILES_ + it) * JCA_) * 512;
    f32x4 C0 = {0.f, 0.f, 0.f, 0.f}, C1 = {0.f, 0.f, 0.f, 0.f};
#pragma unroll
    for (int c = 0; c < JCA_; ++c) {
        C0 += *(const f32x4*)&part[pb + c * 512 + lane * 4];
        C1 += *(const f32x4*)&part[pb + c * 512 + 256 + lane * 4];
    }

    size_t lb = (((size_t)(b * H_ + h) * ITILES_ + it) * JCA_) * 48;
    if (lane < 16) {
        float lt = 0.f, At = 0.f, nzt = 0.f;
#pragma unroll
        for (int c = 0; c < JCA_; ++c) {
            lt  += lpart[lb + c * 48 + lane];
            At  += lpart[lb + c * 48 + 16 + lane];
            nzt += lpart[lb + c * 48 + 32 + lane];
        }
        ldsl[h * 16 + lane] = lt;
        float u = nzt, e = At / lt;
#pragma unroll
        for (int off = 8; off; off >>= 1) { u += __shfl_down(u, off); e += __shfl_down(e, off); }
        if (lane == 0) lossbuf[blk * H_ + h] = make_float2(u, e);
    }
    __syncthreads();
#pragma unroll
    for (int dt = 0; dt < 2; ++dt) {
        int c = h * FP_ + dt * 16 + col;
        float sc = rsqrtf(mvar[c] + 1e-3f) * gamma[c];
        float sh = beta[c] - mmean[c] * sc;
        float bi = bias[c];
        f32x4 Cv = dt ? C1 : C0;
#pragma unroll
        for (int rr = 0; rr < 4; ++rr) {
            int row = quad * 4 + rr;
            float node = Cv[rr] / ldsl[h * 16 + row] + bi;
            float o = node * sc + sh;
            ldso[row * 132 + c] = o > 0.f ? o : 0.f;
        }
    }
    __syncthreads();
#pragma unroll
    for (int ps = 0; ps < 2; ++ps) {
        int row = ps * 8 + (t >> 5);
        int c4 = (t & 31) * 4;
        *(float4*)(out + ((size_t)b * N_ + it * IT_ + row) * C_ + c4) =
            *(const float4*)&ldso[row * 132 + c4];
    }
}

// ---------------------------------------------------------------- kernel 4
__global__ __launch_bounds__(256) void loss_kernel(
    const float2* __restrict__ lossbuf, float* __restrict__ out)
{
    float u = 0.f, e = 0.f;
    for (int idx = threadIdx.x; idx < B_ * ITILES_ * H_; idx += 256) {
        float2 v = lossbuf[idx];
        u += v.x; e += v.y;
    }
    __shared__ float su[256], se[256];
    su[threadIdx.x] = u; se[threadIdx.x] = e;
    __syncthreads();
    for (int o = 128; o; o >>= 1) {
        if (threadIdx.x < o) {
            su[threadIdx.x] += su[threadIdx.x + o];
            se[threadIdx.x] += se[threadIdx.x + o];
        }
        __syncthreads();
    }
    if (threadIdx.x == 0) {
        out[(size_t)B_ * N_ * C_]     = su[0] * (1.f / N_);  // uloss
        out[(size_t)B_ * N_ * C_ + 1] = se[0] * (1.f / N_);  // eloss
    }
}

// ---------------------------------------------------------------- launch
extern "C" void kernel_launch(void* const* d_in, const int* in_sizes, int n_in,
                              void* d_out, int out_size, void* d_ws, size_t ws_size,
                              hipStream_t stream)
{
    const float* x         = (const float*)d_in[0];
    const float* adj       = (const float*)d_in[1];
    const float* attn_mask = (const float*)d_in[2];
    const float* W         = (const float*)d_in[3];
    const float* a_self    = (const float*)d_in[4];
    const float* a_neigh   = (const float*)d_in[5];
    const float* bias      = (const float*)d_in[6];
    const float* gamma     = (const float*)d_in[7];
    const float* beta      = (const float*)d_in[8];
    const float* mmean     = (const float*)d_in[9];
    const float* mvar      = (const float*)d_in[10];
    float* out = (float*)d_out;

    float* ws = (float*)d_ws;
    unsigned short* featsT = (unsigned short*)ws;                     // 1,048,576 u16
    float* sbuf  = ws + 524288;                                       //    32,768 f
    float* tbuf  = sbuf + (size_t)B_ * H_ * N_;                       //    32,768 f
    float* part  = tbuf + (size_t)B_ * H_ * N_;                       // 8,388,608 f
    float* lpart = part + (size_t)B_ * H_ * ITILES_ * JCA_ * 2 * 256; //   786,432 f
    float* lossb = lpart + (size_t)B_ * H_ * ITILES_ * JCA_ * 48;     //     4,096 f

    hipLaunchKernelGGL(prep_kernel, dim3(B_ * 32), dim3(256), 0, stream,
                       x, W, a_self, a_neigh, featsT, sbuf, tbuf);
    hipLaunchKernelGGL(attn_kernel, dim3(B_ * ITILES_ * JCA_), dim3(256), 0, stream,
                       adj, attn_mask, featsT, sbuf, tbuf, part, lpart);
    hipLaunchKernelGGL(final_kernel, dim3(B_ * ITILES_), dim3(256), 0, stream,
                       part, lpart, bias, gamma, beta, mmean, mvar,
                       (float2*)lossb, out);
    hipLaunchKernelGGL(loss_kernel, dim3(1), dim3(256), 0, stream,
                       (const float2*)lossb, out);
}

// Round 7
// 229.357 us; speedup vs baseline: 1.0892x; 1.0892x over previous
//
#include <hip/hip_runtime.h>

// GraphAttention fused forward for MI355X (gfx950).
// MFMA PV + double-buffered LDS staging of adj/mask/t in the attn kernel.
// B=4, N=2048, F=64, FP=32, H=4.  Output: [B,N,H*FP] f32 ++ uloss ++ eloss.

#define B_ 4
#define N_ 2048
#define F_ 64
#define FP_ 32
#define H_ 4
#define C_ 128
#define IT_ 16                 // i-rows per attn block
#define ITILES_ (N_ / IT_)     // 128
#define JCA_ 4                 // j-chunks (partial accumulation)
#define JSPANA_ (N_ / JCA_)    // 512
#define JST_ 128               // j per LDS stage
#define NST_ (JSPANA_ / JST_)  // 4 stages
#define KCS_ (JST_ / 32)       // 4 MFMA k-steps per stage
#define APAD_ 132              // padded LDS row: balanced b128 access

typedef __attribute__((ext_vector_type(8))) short short8v;   // 8 bf16 = 4 VGPRs
typedef __attribute__((ext_vector_type(4))) float f32x4;     // MFMA C/D

__device__ __forceinline__ unsigned short f2bf(float f) {    // RNE fp32->bf16
    unsigned u = __float_as_uint(f);
    u += 0x7fffu + ((u >> 16) & 1u);
    return (unsigned short)(u >> 16);
}

// ---------------------------------------------------------------- kernel 1
// feats = x@W per head via MFMA; writes featsT bf16 [b][h][d][n] + s,t fp32.
__global__ __launch_bounds__(256) void prep_kernel(
    const float* __restrict__ x, const float* __restrict__ W,
    const float* __restrict__ a_self, const float* __restrict__ a_neigh,
    unsigned short* __restrict__ featsT, float* __restrict__ sbuf,
    float* __restrict__ tbuf)
{
    int blk = blockIdx.x;              // b*32 + nt
    int b = blk >> 5, nt = blk & 31;
    int n0 = nt << 6;
    int t = threadIdx.x, h = t >> 6, lane = t & 63;
    int quad = lane >> 4, col = lane & 15;

    short8v bw[2][2];
    const float* Wh = W + (size_t)h * F_ * FP_;
#pragma unroll
    for (int kc = 0; kc < 2; ++kc)
#pragma unroll
        for (int dt = 0; dt < 2; ++dt)
#pragma unroll
            for (int e = 0; e < 8; ++e) {
                int f = kc * 32 + quad * 8 + e;
                bw[kc][dt][e] = (short)f2bf(Wh[f * FP_ + dt * 16 + col]);
            }
    float as0 = a_self[h * FP_ + col],  as1 = a_self[h * FP_ + 16 + col];
    float an0 = a_neigh[h * FP_ + col], an1 = a_neigh[h * FP_ + 16 + col];
    size_t hrow = ((size_t)b * H_ + h) * N_;
    size_t ftb  = ((size_t)b * H_ + h) * FP_;

    for (int ms = 0; ms < 4; ++ms) {
        int row = n0 + ms * 16 + col;          // A row m = lane&15
        const float* xr = x + ((size_t)b * N_ + row) * F_;
        f32x4 acc0 = {0.f, 0.f, 0.f, 0.f}, acc1 = {0.f, 0.f, 0.f, 0.f};
#pragma unroll
        for (int kc = 0; kc < 2; ++kc) {
            float4 x0 = *(const float4*)(xr + kc * 32 + quad * 8);
            float4 x1 = *(const float4*)(xr + kc * 32 + quad * 8 + 4);
            short8v av;
            av[0] = (short)f2bf(x0.x); av[1] = (short)f2bf(x0.y);
            av[2] = (short)f2bf(x0.z); av[3] = (short)f2bf(x0.w);
            av[4] = (short)f2bf(x1.x); av[5] = (short)f2bf(x1.y);
            av[6] = (short)f2bf(x1.z); av[7] = (short)f2bf(x1.w);
            acc0 = __builtin_amdgcn_mfma_f32_16x16x32_bf16(av, bw[kc][0], acc0, 0, 0, 0);
            acc1 = __builtin_amdgcn_mfma_f32_16x16x32_bf16(av, bw[kc][1], acc1, 0, 0, 0);
        }
        {   // C layout: row = quad*4+rr, col = lane&15 (verified m89/m91)
            ushort4 v0, v1;
            v0.x = f2bf(acc0[0]); v0.y = f2bf(acc0[1]);
            v0.z = f2bf(acc0[2]); v0.w = f2bf(acc0[3]);
            v1.x = f2bf(acc1[0]); v1.y = f2bf(acc1[1]);
            v1.z = f2bf(acc1[2]); v1.w = f2bf(acc1[3]);
            size_t nidx = (size_t)n0 + ms * 16 + quad * 4;
            *(ushort4*)(featsT + (ftb + col) * N_ + nidx)      = v0;
            *(ushort4*)(featsT + (ftb + 16 + col) * N_ + nidx) = v1;
        }
#pragma unroll
        for (int rr = 0; rr < 4; ++rr) {
            float sv = acc0[rr] * as0 + acc1[rr] * as1;
            float tv = acc0[rr] * an0 + acc1[rr] * an1;
#pragma unroll
            for (int off = 8; off; off >>= 1) {
                sv += __shfl_down(sv, off);
                tv += __shfl_down(tv, off);
            }
            if (col == 0) {
                int n = n0 + ms * 16 + quad * 4 + rr;
                sbuf[hrow + n] = sv;
                tbuf[hrow + n] = tv;
            }
        }
    }
}

// ---------------------------------------------------------------- kernel 2
// Block = (b, 16-row i-tile, jc); 4 waves = 4 heads.
// Double-buffered LDS staging: global loads for stage st+1 issued before the
// barrier, consumed next iteration -> latency hidden behind ~1.1K cyc compute.
__global__ __launch_bounds__(256, 4) void attn_kernel(
    const float* __restrict__ adj, const float* __restrict__ msk,
    const unsigned short* __restrict__ featsT,
    const float* __restrict__ sbuf, const float* __restrict__ tbuf,
    float* __restrict__ part, float* __restrict__ lpart)
{
    __shared__ float lds_adj[2][IT_ * APAD_];
    __shared__ float lds_msk[2][IT_ * APAD_];
    __shared__ float lds_t[2][H_ * JST_];

    int blk = blockIdx.x;
    int jc = blk & (JCA_ - 1);
    int it = (blk >> 2) & (ITILES_ - 1);
    int b  = blk >> 9;
    int t = threadIdx.x, h = t >> 6, lane = t & 63;
    int quad = lane >> 4, r = lane & 15;
    int i0 = it * IT_;
    int jbase = jc * JSPANA_;

    size_t hrow = ((size_t)b * H_ + h) * N_;
    float si = sbuf[hrow + i0 + r];
    const unsigned short* ft0 = featsT + (((size_t)b * H_ + h) * FP_ + r) * N_
                                + jbase + quad * 8;
    const unsigned short* ft1 = ft0 + (size_t)16 * N_;

    // staging coords: thread t stages row srow, float4 pair at sj; t float2
    int srow = t >> 4, sj = (t & 15) * 8;
    int th = t >> 6, tj = (t & 63) * 2;
    const float* adjs = adj + ((size_t)b * N_ + i0 + srow) * N_ + jbase + sj;
    const float* msks = msk + ((size_t)b * N_ + i0 + srow) * N_ + jbase + sj;
    const float* tbs  = tbuf + ((size_t)b * H_ + th) * N_ + jbase + tj;

    f32x4 acc0 = {0.f, 0.f, 0.f, 0.f}, acc1 = {0.f, 0.f, 0.f, 0.f};
    float l = 0.f, A = 0.f, nz = 0.f;

    // stage-0 loads
    float4 sa0 = *(const float4*)(adjs);
    float4 sa1 = *(const float4*)(adjs + 4);
    float4 sm0 = *(const float4*)(msks);
    float4 sm1 = *(const float4*)(msks + 4);
    float2 stt = *(const float2*)(tbs);

#pragma unroll
    for (int st = 0; st < NST_; ++st) {
        int cur = st & 1;
        // commit staged regs to LDS (forces vmcnt wait here, after prev compute)
        *(float4*)&lds_adj[cur][srow * APAD_ + sj]     = sa0;
        *(float4*)&lds_adj[cur][srow * APAD_ + sj + 4] = sa1;
        *(float4*)&lds_msk[cur][srow * APAD_ + sj]     = sm0;
        *(float4*)&lds_msk[cur][srow * APAD_ + sj + 4] = sm1;
        *(float2*)&lds_t[cur][th * JST_ + tj]          = stt;
        // issue next stage's global loads (in flight during this compute)
        if (st + 1 < NST_) {
            int jn = (st + 1) * JST_;
            sa0 = *(const float4*)(adjs + jn);
            sa1 = *(const float4*)(adjs + jn + 4);
            sm0 = *(const float4*)(msks + jn);
            sm1 = *(const float4*)(msks + jn + 4);
            stt = *(const float2*)(tbs + jn);
        }
        __syncthreads();
#pragma unroll
        for (int kc = 0; kc < KCS_; ++kc) {
            int jt = kc * 32 + quad * 8;               // col within stage
            int jl = st * JST_ + jt;                   // col within span
            float4 a0 = *(const float4*)&lds_adj[cur][r * APAD_ + jt];
            float4 a1 = *(const float4*)&lds_adj[cur][r * APAD_ + jt + 4];
            float4 m0 = *(const float4*)&lds_msk[cur][r * APAD_ + jt];
            float4 m1 = *(const float4*)&lds_msk[cur][r * APAD_ + jt + 4];
            float4 t0 = *(const float4*)&lds_t[cur][h * JST_ + jt];
            float4 t1 = *(const float4*)&lds_t[cur][h * JST_ + jt + 4];
            short8v bv0 = *(const short8v*)(ft0 + jl);
            short8v bv1 = *(const short8v*)(ft1 + jl);
            float av[8] = {a0.x, a0.y, a0.z, a0.w, a1.x, a1.y, a1.z, a1.w};
            float mv[8] = {m0.x, m0.y, m0.z, m0.w, m1.x, m1.y, m1.z, m1.w};
            float tv[8] = {t0.x, t0.y, t0.z, t0.w, t1.x, t1.y, t1.z, t1.w};
            short8v ap;
#pragma unroll
            for (int q = 0; q < 8; ++q) {
                float dv = si + tv[q];
                dv = fmaxf(dv, 0.2f * dv);            // LeakyReLU(0.2)
                dv += mv[q];
                float e = __expf(dv);                 // bounded: no max-subtract
                float p = e * av[q];
                l += e; A += p;
                nz += (av[q] == 0.f ? 1.f : 0.f) - (p == 0.f ? 1.f : 0.f);
                ap[q] = (short)(__float_as_uint(p) >> 16);   // truncate->bf16
            }
            acc0 = __builtin_amdgcn_mfma_f32_16x16x32_bf16(ap, bv0, acc0, 0, 0, 0);
            acc1 = __builtin_amdgcn_mfma_f32_16x16x32_bf16(ap, bv1, acc1, 0, 0, 0);
        }
        __syncthreads();          // compute done before buffer reuse (st+2)
    }
    // row totals live in lanes 0-15 after folding the 4 k-group lanes
    l  += __shfl_down(l, 32);  l  += __shfl_down(l, 16);
    A  += __shfl_down(A, 32);  A  += __shfl_down(A, 16);
    nz += __shfl_down(nz, 32); nz += __shfl_down(nz, 16);

    size_t pb = ((((size_t)(b * H_ + h) * ITILES_ + it) * JCA_ + jc) * 2) * 256;
    *(f32x4*)&part[pb + lane * 4]       = acc0;   // raw C-frag, coalesced
    *(f32x4*)&part[pb + 256 + lane * 4] = acc1;
    if (lane < 16) {
        size_t lb = (((size_t)(b * H_ + h) * ITILES_ + it) * JCA_ + jc) * 48;
        lpart[lb + lane]      = l;
        lpart[lb + 16 + lane] = A;
        lpart[lb + 32 + lane] = nz;
    }
}

// ---------------------------------------------------------------- kernel 3
// Block = (b, i-tile). Merge jc partials (raw C-frag layout), /l, bias, BN,
// ReLU, LDS transpose, coalesced out; per-(block,h) loss partials.
__global__ __launch_bounds__(256) void final_kernel(
    const float* __restrict__ part, const float* __restrict__ lpart,
    const float* __restrict__ bias, const float* __restrict__ gamma,
    const float* __restrict__ beta, const float* __restrict__ mmean,
    const float* __restrict__ mvar, float2* __restrict__ lossbuf,
    float* __restrict__ out)
{
    __shared__ float ldsl[H_ * 16];
    __shared__ float ldso[IT_ * 132];
    int blk = blockIdx.x;              // b*128 + it
    int b = blk >> 7, it = blk & 127;
    int t = threadIdx.x, h = t >> 6, lane = t & 63;
    int quad = lane >> 4, col = lane & 15;

    size_t pb = (((size_t)(b * H_ + h) * ITILES_ + it) * JCA_) * 512;
    f32x4 C0 = {0.f, 0.f, 0.f, 0.f}, C1 = {0.f, 0.f, 0.f, 0.f};
#pragma unroll
    for (int c = 0; c < JCA_; ++c) {
        C0 += *(const f32x4*)&part[pb + c * 512 + lane * 4];
        C1 += *(const f32x4*)&part[pb + c * 512 + 256 + lane * 4];
    }

    size_t lb = (((size_t)(b * H_ + h) * ITILES_ + it) * JCA_) * 48;
    if (lane < 16) {
        float lt = 0.f, At = 0.f, nzt = 0.f;
#pragma unroll
        for (int c = 0; c < JCA_; ++c) {
            lt  += lpart[lb + c * 48 + lane];
            At  += lpart[lb + c * 48 + 16 + lane];
            nzt += lpart[lb + c * 48 + 32 + lane];
        }
        ldsl[h * 16 + lane] = lt;
        float u = nzt, e = At / lt;
#pragma unroll
        for (int off = 8; off; off >>= 1) { u += __shfl_down(u, off); e += __shfl_down(e, off); }
        if (lane == 0) lossbuf[blk * H_ + h] = make_float2(u, e);
    }
    __syncthreads();
#pragma unroll
    for (int dt = 0; dt < 2; ++dt) {
        int c = h * FP_ + dt * 16 + col;
        float sc = rsqrtf(mvar[c] + 1e-3f) * gamma[c];
        float sh = beta[c] - mmean[c] * sc;
        float bi = bias[c];
        f32x4 Cv = dt ? C1 : C0;
#pragma unroll
        for (int rr = 0; rr < 4; ++rr) {
            int row = quad * 4 + rr;
            float node = Cv[rr] / ldsl[h * 16 + row] + bi;
            float o = node * sc + sh;
            ldso[row * 132 + c] = o > 0.f ? o : 0.f;
        }
    }
    __syncthreads();
#pragma unroll
    for (int ps = 0; ps < 2; ++ps) {
        int row = ps * 8 + (t >> 5);
        int c4 = (t & 31) * 4;
        *(float4*)(out + ((size_t)b * N_ + it * IT_ + row) * C_ + c4) =
            *(const float4*)&ldso[row * 132 + c4];
    }
}

// ---------------------------------------------------------------- kernel 4
__global__ __launch_bounds__(256) void loss_kernel(
    const float2* __restrict__ lossbuf, float* __restrict__ out)
{
    float u = 0.f, e = 0.f;
    for (int idx = threadIdx.x; idx < B_ * ITILES_ * H_; idx += 256) {
        float2 v = lossbuf[idx];
        u += v.x; e += v.y;
    }
    __shared__ float su[256], se[256];
    su[threadIdx.x] = u; se[threadIdx.x] = e;
    __syncthreads();
    for (int o = 128; o; o >>= 1) {
        if (threadIdx.x < o) {
            su[threadIdx.x] += su[threadIdx.x + o];
            se[threadIdx.x] += se[threadIdx.x + o];
        }
        __syncthreads();
    }
    if (threadIdx.x == 0) {
        out[(size_t)B_ * N_ * C_]     = su[0] * (1.f / N_);  // uloss
        out[(size_t)B_ * N_ * C_ + 1] = se[0] * (1.f / N_);  // eloss
    }
}

// ---------------------------------------------------------------- launch
extern "C" void kernel_launch(void* const* d_in, const int* in_sizes, int n_in,
                              void* d_out, int out_size, void* d_ws, size_t ws_size,
                              hipStream_t stream)
{
    const float* x         = (const float*)d_in[0];
    const float* adj       = (const float*)d_in[1];
    const float* attn_mask = (const float*)d_in[2];
    const float* W         = (const float*)d_in[3];
    const float* a_self    = (const float*)d_in[4];
    const float* a_neigh   = (const float*)d_in[5];
    const float* bias      = (const float*)d_in[6];
    const float* gamma     = (const float*)d_in[7];
    const float* beta      = (const float*)d_in[8];
    const float* mmean     = (const float*)d_in[9];
    const float* mvar      = (const float*)d_in[10];
    float* out = (float*)d_out;

    float* ws = (float*)d_ws;
    unsigned short* featsT = (unsigned short*)ws;                     // 1,048,576 u16
    float* sbuf  = ws + 524288;                                       //    32,768 f
    float* tbuf  = sbuf + (size_t)B_ * H_ * N_;                       //    32,768 f
    float* part  = tbuf + (size_t)B_ * H_ * N_;                       // 4,194,304 f
    float* lpart = part + (size_t)B_ * H_ * ITILES_ * JCA_ * 2 * 256; //   393,216 f
    float* lossb = lpart + (size_t)B_ * H_ * ITILES_ * JCA_ * 48;     //     4,096 f

    hipLaunchKernelGGL(prep_kernel, dim3(B_ * 32), dim3(256), 0, stream,
                       x, W, a_self, a_neigh, featsT, sbuf, tbuf);
    hipLaunchKernelGGL(attn_kernel, dim3(B_ * ITILES_ * JCA_), dim3(256), 0, stream,
                       adj, attn_mask, featsT, sbuf, tbuf, part, lpart);
    hipLaunchKernelGGL(final_kernel, dim3(B_ * ITILES_), dim3(256), 0, stream,
                       part, lpart, bias, gamma, beta, mmean, mvar,
                       (float2*)lossb, out);
    hipLaunchKernelGGL(loss_kernel, dim3(1), dim3(256), 0, stream,
                       (const float2*)lossb, out);
}

// Round 8
// 217.006 us; speedup vs baseline: 1.1512x; 1.0569x over previous
//
#include <hip/hip_runtime.h>

// GraphAttention fused forward for MI355X (gfx950).
// MFMA PV, single-buffered LDS staging, occupancy-maximized (8 blocks/CU).
// B=4, N=2048, F=64, FP=32, H=4.  Output: [B,N,H*FP] f32 ++ uloss ++ eloss.

#define B_ 4
#define N_ 2048
#define F_ 64
#define FP_ 32
#define H_ 4
#define C_ 128
#define IT_ 16                 // i-rows per attn block
#define ITILES_ (N_ / IT_)     // 128
#define JCA_ 8                 // j-chunks -> grid 4096 = 16 blocks/CU queued
#define JSPANA_ (N_ / JCA_)    // 256
#define JST_ 64                // j per LDS stage (small LDS -> 8 blocks/CU)
#define NST_ (JSPANA_ / JST_)  // 4 stages
#define KCS_ (JST_ / 32)       // 2 MFMA k-steps per stage
#define APAD_ 68               // row stride: bank-quad (r+2q)%8 uniform -> ~conflict-free

typedef __attribute__((ext_vector_type(8))) short short8v;   // 8 bf16 = 4 VGPRs
typedef __attribute__((ext_vector_type(4))) float f32x4;     // MFMA C/D

__device__ __forceinline__ unsigned short f2bf(float f) {    // RNE fp32->bf16
    unsigned u = __float_as_uint(f);
    u += 0x7fffu + ((u >> 16) & 1u);
    return (unsigned short)(u >> 16);
}

// ---------------------------------------------------------------- kernel 1
// feats = x@W per head via MFMA; writes featsT bf16 [b][h][d][n] + s,t fp32.
__global__ __launch_bounds__(256) void prep_kernel(
    const float* __restrict__ x, const float* __restrict__ W,
    const float* __restrict__ a_self, const float* __restrict__ a_neigh,
    unsigned short* __restrict__ featsT, float* __restrict__ sbuf,
    float* __restrict__ tbuf)
{
    int blk = blockIdx.x;              // b*32 + nt
    int b = blk >> 5, nt = blk & 31;
    int n0 = nt << 6;
    int t = threadIdx.x, h = t >> 6, lane = t & 63;
    int quad = lane >> 4, col = lane & 15;

    short8v bw[2][2];
    const float* Wh = W + (size_t)h * F_ * FP_;
#pragma unroll
    for (int kc = 0; kc < 2; ++kc)
#pragma unroll
        for (int dt = 0; dt < 2; ++dt)
#pragma unroll
            for (int e = 0; e < 8; ++e) {
                int f = kc * 32 + quad * 8 + e;
                bw[kc][dt][e] = (short)f2bf(Wh[f * FP_ + dt * 16 + col]);
            }
    float as0 = a_self[h * FP_ + col],  as1 = a_self[h * FP_ + 16 + col];
    float an0 = a_neigh[h * FP_ + col], an1 = a_neigh[h * FP_ + 16 + col];
    size_t hrow = ((size_t)b * H_ + h) * N_;
    size_t ftb  = ((size_t)b * H_ + h) * FP_;

    for (int ms = 0; ms < 4; ++ms) {
        int row = n0 + ms * 16 + col;          // A row m = lane&15
        const float* xr = x + ((size_t)b * N_ + row) * F_;
        f32x4 acc0 = {0.f, 0.f, 0.f, 0.f}, acc1 = {0.f, 0.f, 0.f, 0.f};
#pragma unroll
        for (int kc = 0; kc < 2; ++kc) {
            float4 x0 = *(const float4*)(xr + kc * 32 + quad * 8);
            float4 x1 = *(const float4*)(xr + kc * 32 + quad * 8 + 4);
            short8v av;
            av[0] = (short)f2bf(x0.x); av[1] = (short)f2bf(x0.y);
            av[2] = (short)f2bf(x0.z); av[3] = (short)f2bf(x0.w);
            av[4] = (short)f2bf(x1.x); av[5] = (short)f2bf(x1.y);
            av[6] = (short)f2bf(x1.z); av[7] = (short)f2bf(x1.w);
            acc0 = __builtin_amdgcn_mfma_f32_16x16x32_bf16(av, bw[kc][0], acc0, 0, 0, 0);
            acc1 = __builtin_amdgcn_mfma_f32_16x16x32_bf16(av, bw[kc][1], acc1, 0, 0, 0);
        }
        {   // C layout: row = quad*4+rr, col = lane&15 (verified m89/m91)
            ushort4 v0, v1;
            v0.x = f2bf(acc0[0]); v0.y = f2bf(acc0[1]);
            v0.z = f2bf(acc0[2]); v0.w = f2bf(acc0[3]);
            v1.x = f2bf(acc1[0]); v1.y = f2bf(acc1[1]);
            v1.z = f2bf(acc1[2]); v1.w = f2bf(acc1[3]);
            size_t nidx = (size_t)n0 + ms * 16 + quad * 4;
            *(ushort4*)(featsT + (ftb + col) * N_ + nidx)      = v0;
            *(ushort4*)(featsT + (ftb + 16 + col) * N_ + nidx) = v1;
        }
#pragma unroll
        for (int rr = 0; rr < 4; ++rr) {
            float sv = acc0[rr] * as0 + acc1[rr] * as1;
            float tv = acc0[rr] * an0 + acc1[rr] * an1;
#pragma unroll
            for (int off = 8; off; off >>= 1) {
                sv += __shfl_down(sv, off);
                tv += __shfl_down(tv, off);
            }
            if (col == 0) {
                int n = n0 + ms * 16 + quad * 4 + rr;
                sbuf[hrow + n] = sv;
                tbuf[hrow + n] = tv;
            }
        }
    }
}

// ---------------------------------------------------------------- kernel 2
// Block = (b, 16-row i-tile, jc); 4 waves = 4 heads. Single-buffered LDS
// staging, small footprint -> 8 blocks/CU resident; cross-block TLP hides
// the stage drains. Conflict-free APAD=68 stride.
__global__ __launch_bounds__(256, 8) void attn_kernel(
    const float* __restrict__ adj, const float* __restrict__ msk,
    const unsigned short* __restrict__ featsT,
    const float* __restrict__ sbuf, const float* __restrict__ tbuf,
    float* __restrict__ part, float* __restrict__ lpart)
{
    __shared__ float lds_adj[IT_ * APAD_];
    __shared__ float lds_msk[IT_ * APAD_];
    __shared__ float lds_t[H_ * JST_];

    int blk = blockIdx.x;
    int jc = blk & (JCA_ - 1);
    int it = (blk >> 3) & (ITILES_ - 1);
    int b  = blk >> 10;
    int t = threadIdx.x, h = t >> 6, lane = t & 63;
    int quad = lane >> 4, r = lane & 15;
    int i0 = it * IT_;
    int jbase = jc * JSPANA_;

    size_t hrow = ((size_t)b * H_ + h) * N_;
    float si = sbuf[hrow + i0 + r];
    const unsigned short* ft0 = featsT + (((size_t)b * H_ + h) * FP_ + r) * N_
                                + jbase + quad * 8;
    const unsigned short* ft1 = ft0 + (size_t)16 * N_;

    // staging coords: thread t stages one float4 of row srow at f4 slot sf4
    int srow = t >> 4, sf4 = (t & 15) * 4;
    const float* adjs = adj + ((size_t)b * N_ + i0 + srow) * N_ + jbase + sf4;
    const float* msks = msk + ((size_t)b * N_ + i0 + srow) * N_ + jbase + sf4;
    const float* tbs  = tbuf + ((size_t)b * H_ + h) * N_ + jbase + lane;

    f32x4 acc0 = {0.f, 0.f, 0.f, 0.f}, acc1 = {0.f, 0.f, 0.f, 0.f};
    float l = 0.f, A = 0.f, nz = 0.f;

#pragma unroll
    for (int st = 0; st < NST_; ++st) {
        int j0 = st * JST_;
        __syncthreads();                       // prev compute done
        *(float4*)&lds_adj[srow * APAD_ + sf4] = *(const float4*)(adjs + j0);
        *(float4*)&lds_msk[srow * APAD_ + sf4] = *(const float4*)(msks + j0);
        lds_t[h * JST_ + lane] = tbs[j0];
        __syncthreads();
#pragma unroll
        for (int kc = 0; kc < KCS_; ++kc) {
            int jt = kc * 32 + quad * 8;               // col within stage
            int jl = j0 + jt;                          // col within span
            float4 a0 = *(const float4*)&lds_adj[r * APAD_ + jt];
            float4 a1 = *(const float4*)&lds_adj[r * APAD_ + jt + 4];
            float4 m0 = *(const float4*)&lds_msk[r * APAD_ + jt];
            float4 m1 = *(const float4*)&lds_msk[r * APAD_ + jt + 4];
            float4 t0 = *(const float4*)&lds_t[h * JST_ + jt];      // broadcast
            float4 t1 = *(const float4*)&lds_t[h * JST_ + jt + 4];
            short8v bv0 = *(const short8v*)(ft0 + jl);
            short8v bv1 = *(const short8v*)(ft1 + jl);
            float av[8] = {a0.x, a0.y, a0.z, a0.w, a1.x, a1.y, a1.z, a1.w};
            float mv[8] = {m0.x, m0.y, m0.z, m0.w, m1.x, m1.y, m1.z, m1.w};
            float tv[8] = {t0.x, t0.y, t0.z, t0.w, t1.x, t1.y, t1.z, t1.w};
            short8v ap;
#pragma unroll
            for (int q = 0; q < 8; ++q) {
                float dv = si + tv[q];
                dv = fmaxf(dv, 0.2f * dv);            // LeakyReLU(0.2)
                dv += mv[q];
                float e = __expf(dv);                 // bounded: no max-subtract
                float p = e * av[q];
                l += e; A += p;
                nz += (av[q] == 0.f ? 1.f : 0.f) - (p == 0.f ? 1.f : 0.f);
                ap[q] = (short)f2bf(p);               // RNE (truncation broke absmax)
            }
            acc0 = __builtin_amdgcn_mfma_f32_16x16x32_bf16(ap, bv0, acc0, 0, 0, 0);
            acc1 = __builtin_amdgcn_mfma_f32_16x16x32_bf16(ap, bv1, acc1, 0, 0, 0);
        }
    }
    // row totals live in lanes 0-15 after folding the 4 k-group lanes
    l  += __shfl_down(l, 32);  l  += __shfl_down(l, 16);
    A  += __shfl_down(A, 32);  A  += __shfl_down(A, 16);
    nz += __shfl_down(nz, 32); nz += __shfl_down(nz, 16);

    size_t pb = ((((size_t)(b * H_ + h) * ITILES_ + it) * JCA_ + jc) * 2) * 256;
    *(f32x4*)&part[pb + lane * 4]       = acc0;   // raw C-frag, coalesced
    *(f32x4*)&part[pb + 256 + lane * 4] = acc1;
    if (lane < 16) {
        size_t lb = (((size_t)(b * H_ + h) * ITILES_ + it) * JCA_ + jc) * 48;
        lpart[lb + lane]      = l;
        lpart[lb + 16 + lane] = A;
        lpart[lb + 32 + lane] = nz;
    }
}

// ---------------------------------------------------------------- kernel 3
// Block = (b, i-tile). Merge jc partials (raw C-frag layout), /l, bias, BN,
// ReLU, LDS transpose, coalesced out; per-(block,h) loss partials.
__global__ __launch_bounds__(256) void final_kernel(
    const float* __restrict__ part, const float* __restrict__ lpart,
    const float* __restrict__ bias, const float* __restrict__ gamma,
    const float* __restrict__ beta, const float* __restrict__ mmean,
    const float* __restrict__ mvar, float2* __restrict__ lossbuf,
    float* __restrict__ out)
{
    __shared__ float ldsl[H_ * 16];
    __shared__ float ldso[IT_ * 132];
    int blk = blockIdx.x;              // b*128 + it
    int b = blk >> 7, it = blk & 127;
    int t = threadIdx.x, h = t >> 6, lane = t & 63;
    int quad = lane >> 4, col = lane & 15;

    size_t pb = (((size_t)(b * H_ + h) * ITILES_ + it) * JCA_) * 512;
    f32x4 C0 = {0.f, 0.f, 0.f, 0.f}, C1 = {0.f, 0.f, 0.f, 0.f};
#pragma unroll
    for (int c = 0; c < JCA_; ++c) {
        C0 += *(const f32x4*)&part[pb + c * 512 + lane * 4];
        C1 += *(const f32x4*)&part[pb + c * 512 + 256 + lane * 4];
    }

    size_t lb = (((size_t)(b * H_ + h) * ITILES_ + it) * JCA_) * 48;
    if (lane < 16) {
        float lt = 0.f, At = 0.f, nzt = 0.f;
#pragma unroll
        for (int c = 0; c < JCA_; ++c) {
            lt  += lpart[lb + c * 48 + lane];
            At  += lpart[lb + c * 48 + 16 + lane];
            nzt += lpart[lb + c * 48 + 32 + lane];
        }
        ldsl[h * 16 + lane] = lt;
        float u = nzt, e = At / lt;
#pragma unroll
        for (int off = 8; off; off >>= 1) { u += __shfl_down(u, off); e += __shfl_down(e, off); }
        if (lane == 0) lossbuf[blk * H_ + h] = make_float2(u, e);
    }
    __syncthreads();
#pragma unroll
    for (int dt = 0; dt < 2; ++dt) {
        int c = h * FP_ + dt * 16 + col;
        float sc = rsqrtf(mvar[c] + 1e-3f) * gamma[c];
        float sh = beta[c] - mmean[c] * sc;
        float bi = bias[c];
        f32x4 Cv = dt ? C1 : C0;
#pragma unroll
        for (int rr = 0; rr < 4; ++rr) {
            int row = quad * 4 + rr;
            float node = Cv[rr] / ldsl[h * 16 + row] + bi;
            float o = node * sc + sh;
            ldso[row * 132 + c] = o > 0.f ? o : 0.f;
        }
    }
    __syncthreads();
#pragma unroll
    for (int ps = 0; ps < 2; ++ps) {
        int row = ps * 8 + (t >> 5);
        int c4 = (t & 31) * 4;
        *(float4*)(out + ((size_t)b * N_ + it * IT_ + row) * C_ + c4) =
            *(const float4*)&ldso[row * 132 + c4];
    }
}

// ---------------------------------------------------------------- kernel 4
__global__ __launch_bounds__(256) void loss_kernel(
    const float2* __restrict__ lossbuf, float* __restrict__ out)
{
    float u = 0.f, e = 0.f;
    for (int idx = threadIdx.x; idx < B_ * ITILES_ * H_; idx += 256) {
        float2 v = lossbuf[idx];
        u += v.x; e += v.y;
    }
    __shared__ float su[256], se[256];
    su[threadIdx.x] = u; se[threadIdx.x] = e;
    __syncthreads();
    for (int o = 128; o; o >>= 1) {
        if (threadIdx.x < o) {
            su[threadIdx.x] += su[threadIdx.x + o];
            se[threadIdx.x] += se[threadIdx.x + o];
        }
        __syncthreads();
    }
    if (threadIdx.x == 0) {
        out[(size_t)B_ * N_ * C_]     = su[0] * (1.f / N_);  // uloss
        out[(size_t)B_ * N_ * C_ + 1] = se[0] * (1.f / N_);  // eloss
    }
}

// ---------------------------------------------------------------- launch
extern "C" void kernel_launch(void* const* d_in, const int* in_sizes, int n_in,
                              void* d_out, int out_size, void* d_ws, size_t ws_size,
                              hipStream_t stream)
{
    const float* x         = (const float*)d_in[0];
    const float* adj       = (const float*)d_in[1];
    const float* attn_mask = (const float*)d_in[2];
    const float* W         = (const float*)d_in[3];
    const float* a_self    = (const float*)d_in[4];
    const float* a_neigh   = (const float*)d_in[5];
    const float* bias      = (const float*)d_in[6];
    const float* gamma     = (const float*)d_in[7];
    const float* beta      = (const float*)d_in[8];
    const float* mmean     = (const float*)d_in[9];
    const float* mvar      = (const float*)d_in[10];
    float* out = (float*)d_out;

    float* ws = (float*)d_ws;
    unsigned short* featsT = (unsigned short*)ws;                     // 1,048,576 u16
    float* sbuf  = ws + 524288;                                       //    32,768 f
    float* tbuf  = sbuf + (size_t)B_ * H_ * N_;                       //    32,768 f
    float* part  = tbuf + (size_t)B_ * H_ * N_;                       // 8,388,608 f
    float* lpart = part + (size_t)B_ * H_ * ITILES_ * JCA_ * 2 * 256; //   786,432 f
    float* lossb = lpart + (size_t)B_ * H_ * ITILES_ * JCA_ * 48;     //     4,096 f

    hipLaunchKernelGGL(prep_kernel, dim3(B_ * 32), dim3(256), 0, stream,
                       x, W, a_self, a_neigh, featsT, sbuf, tbuf);
    hipLaunchKernelGGL(attn_kernel, dim3(B_ * ITILES_ * JCA_), dim3(256), 0, stream,
                       adj, attn_mask, featsT, sbuf, tbuf, part, lpart);
    hipLaunchKernelGGL(final_kernel, dim3(B_ * ITILES_), dim3(256), 0, stream,
                       part, lpart, bias, gamma, beta, mmean, mvar,
                       (float2*)lossb, out);
    hipLaunchKernelGGL(loss_kernel, dim3(1), dim3(256), 0, stream,
                       (const float2*)lossb, out);
}

// Round 9
// 198.473 us; speedup vs baseline: 1.2587x; 1.0934x over previous
//
#include <hip/hip_runtime.h>

// GraphAttention fused forward for MI355X (gfx950).
// MFMA PV, single-buffered LDS staging, 2 i-rows/lane, lean elementwise path.
// B=4, N=2048, F=64, FP=32, H=4.  Output: [B,N,H*FP] f32 ++ uloss ++ eloss.

#define B_ 4
#define N_ 2048
#define F_ 64
#define FP_ 32
#define H_ 4
#define C_ 128
#define IT_ 32                 // i-rows per attn block (2 per lane)
#define ITILES_ (N_ / IT_)     // 64
#define JCA_ 8                 // j-chunks -> grid 2048
#define JSPANA_ (N_ / JCA_)    // 256
#define JST_ 64                // j per LDS stage
#define NST_ (JSPANA_ / JST_)  // 4 stages
#define KCS_ (JST_ / 32)       // 2 MFMA k-steps per stage
#define APAD_ 66               // stores 2-way (free), reads 4-way (1.58x)

typedef __attribute__((ext_vector_type(8))) short short8v;   // 8 bf16 = 4 VGPRs
typedef __attribute__((ext_vector_type(4))) float f32x4;     // MFMA C/D
typedef __attribute__((ext_vector_type(4))) int   int4v;

union PkU { int4v i; short8v s; };

__device__ __forceinline__ unsigned short f2bf(float f) {    // RNE fp32->bf16
    unsigned u = __float_as_uint(f);
    u += 0x7fffu + ((u >> 16) & 1u);
    return (unsigned short)(u >> 16);
}

// 8 elementwise attn values -> l,A accumulate + packed bf16 A-frag dword x4.
// p >= 0 always; round-half-up (u+0x8000) then take hi16 via v_perm pair-pack.
__device__ __forceinline__ void attn_qstep(
    float si, const float* av, const float* mv, const float* tv,
    float& l, float& A, int4v& apk)
{
#pragma unroll
    for (int qq = 0; qq < 4; ++qq) {
        float d0 = si + tv[2 * qq];
        d0 = fmaxf(d0, 0.2f * d0) + mv[2 * qq];       // LeakyReLU(0.2) + mask
        float e0 = __expf(d0);                        // bounded: no max-subtract
        float p0 = e0 * av[2 * qq];
        float d1 = si + tv[2 * qq + 1];
        d1 = fmaxf(d1, 0.2f * d1) + mv[2 * qq + 1];
        float e1 = __expf(d1);
        float p1 = e1 * av[2 * qq + 1];
        l += e0 + e1;
        A += p0 + p1;
        unsigned u0 = __float_as_uint(p0) + 0x8000u;
        unsigned u1 = __float_as_uint(p1) + 0x8000u;
        apk[qq] = (int)__builtin_amdgcn_perm(u1, u0, 0x07060302u); // [p1.hi|p0.hi]
    }
}

// ---------------------------------------------------------------- kernel 1
// feats = x@W per head via MFMA; writes featsT bf16 [b][h][d][n] + s,t fp32.
__global__ __launch_bounds__(256) void prep_kernel(
    const float* __restrict__ x, const float* __restrict__ W,
    const float* __restrict__ a_self, const float* __restrict__ a_neigh,
    unsigned short* __restrict__ featsT, float* __restrict__ sbuf,
    float* __restrict__ tbuf)
{
    int blk = blockIdx.x;              // b*32 + nt
    int b = blk >> 5, nt = blk & 31;
    int n0 = nt << 6;
    int t = threadIdx.x, h = t >> 6, lane = t & 63;
    int quad = lane >> 4, col = lane & 15;

    short8v bw[2][2];
    const float* Wh = W + (size_t)h * F_ * FP_;
#pragma unroll
    for (int kc = 0; kc < 2; ++kc)
#pragma unroll
        for (int dt = 0; dt < 2; ++dt)
#pragma unroll
            for (int e = 0; e < 8; ++e) {
                int f = kc * 32 + quad * 8 + e;
                bw[kc][dt][e] = (short)f2bf(Wh[f * FP_ + dt * 16 + col]);
            }
    float as0 = a_self[h * FP_ + col],  as1 = a_self[h * FP_ + 16 + col];
    float an0 = a_neigh[h * FP_ + col], an1 = a_neigh[h * FP_ + 16 + col];
    size_t hrow = ((size_t)b * H_ + h) * N_;
    size_t ftb  = ((size_t)b * H_ + h) * FP_;

    for (int ms = 0; ms < 4; ++ms) {
        int row = n0 + ms * 16 + col;          // A row m = lane&15
        const float* xr = x + ((size_t)b * N_ + row) * F_;
        f32x4 acc0 = {0.f, 0.f, 0.f, 0.f}, acc1 = {0.f, 0.f, 0.f, 0.f};
#pragma unroll
        for (int kc = 0; kc < 2; ++kc) {
            float4 x0 = *(const float4*)(xr + kc * 32 + quad * 8);
            float4 x1 = *(const float4*)(xr + kc * 32 + quad * 8 + 4);
            short8v av;
            av[0] = (short)f2bf(x0.x); av[1] = (short)f2bf(x0.y);
            av[2] = (short)f2bf(x0.z); av[3] = (short)f2bf(x0.w);
            av[4] = (short)f2bf(x1.x); av[5] = (short)f2bf(x1.y);
            av[6] = (short)f2bf(x1.z); av[7] = (short)f2bf(x1.w);
            acc0 = __builtin_amdgcn_mfma_f32_16x16x32_bf16(av, bw[kc][0], acc0, 0, 0, 0);
            acc1 = __builtin_amdgcn_mfma_f32_16x16x32_bf16(av, bw[kc][1], acc1, 0, 0, 0);
        }
        {   // C layout: row = quad*4+rr, col = lane&15 (verified m89/m91)
            ushort4 v0, v1;
            v0.x = f2bf(acc0[0]); v0.y = f2bf(acc0[1]);
            v0.z = f2bf(acc0[2]); v0.w = f2bf(acc0[3]);
            v1.x = f2bf(acc1[0]); v1.y = f2bf(acc1[1]);
            v1.z = f2bf(acc1[2]); v1.w = f2bf(acc1[3]);
            size_t nidx = (size_t)n0 + ms * 16 + quad * 4;
            *(ushort4*)(featsT + (ftb + col) * N_ + nidx)      = v0;
            *(ushort4*)(featsT + (ftb + 16 + col) * N_ + nidx) = v1;
        }
#pragma unroll
        for (int rr = 0; rr < 4; ++rr) {
            float sv = acc0[rr] * as0 + acc1[rr] * as1;
            float tv = acc0[rr] * an0 + acc1[rr] * an1;
#pragma unroll
            for (int off = 8; off; off >>= 1) {
                sv += __shfl_down(sv, off);
                tv += __shfl_down(tv, off);
            }
            if (col == 0) {
                int n = n0 + ms * 16 + quad * 4 + rr;
                sbuf[hrow + n] = sv;
                tbuf[hrow + n] = tv;
            }
        }
    }
}

// ---------------------------------------------------------------- kernel 2
// Block = (b, 32-row i-tile, jc); 4 waves = 4 heads. Single-buffered LDS
// staging; each lane computes 2 i-rows (r, r+16) -> featsT/t/staging
// amortized 2x. uloss==0 identically (alpha==0 <=> adj==0; no underflow).
__global__ __launch_bounds__(256, 4) void attn_kernel(
    const float* __restrict__ adj, const float* __restrict__ msk,
    const unsigned short* __restrict__ featsT,
    const float* __restrict__ sbuf, const float* __restrict__ tbuf,
    float* __restrict__ part, float* __restrict__ lpart)
{
    __shared__ float lds_adj[IT_ * APAD_];
    __shared__ float lds_msk[IT_ * APAD_];
    __shared__ float lds_t[H_ * JST_];

    int blk = blockIdx.x;
    int jc = blk & (JCA_ - 1);
    int it = (blk >> 3) & (ITILES_ - 1);
    int b  = blk >> 9;
    int t = threadIdx.x, h = t >> 6, lane = t & 63;
    int quad = lane >> 4, r = lane & 15;
    int i0 = it * IT_;
    int jbase = jc * JSPANA_;

    size_t hrow = ((size_t)b * H_ + h) * N_;
    float si0 = sbuf[hrow + i0 + r];
    float si1 = sbuf[hrow + i0 + 16 + r];
    // B-frag: lane(quad,r) holds featsT[d=r][j = slice + quad*8 + e]
    // (quad*8 in the base pointer ONLY — R7/R8 double-added it in the index)
    const unsigned short* ft0 = featsT + (((size_t)b * H_ + h) * FP_ + r) * N_
                                + jbase + quad * 8;
    const unsigned short* ft1 = ft0 + (size_t)16 * N_;

    // staging coords: thread t stages rows srow & srow+16, float4 slot sf4
    int srow = t >> 4, sf4 = (t & 15) * 4;
    const float* adjs = adj + ((size_t)b * N_ + i0 + srow) * N_ + jbase + sf4;
    const float* msks = msk + ((size_t)b * N_ + i0 + srow) * N_ + jbase + sf4;
    int th = t >> 6, tj = t & 63;
    const float* tbs = tbuf + ((size_t)b * H_ + th) * N_ + jbase + tj;

    f32x4 acc00 = {0.f,0.f,0.f,0.f}, acc01 = {0.f,0.f,0.f,0.f};
    f32x4 acc10 = {0.f,0.f,0.f,0.f}, acc11 = {0.f,0.f,0.f,0.f};
    float l0 = 0.f, A0 = 0.f, l1 = 0.f, A1 = 0.f;

#pragma unroll
    for (int st = 0; st < NST_; ++st) {
        int j0 = st * JST_;
        __syncthreads();                       // prev compute done
        *(float4*)&lds_adj[srow * APAD_ + sf4] = *(const float4*)(adjs + j0);
        *(float4*)&lds_adj[(srow + 16) * APAD_ + sf4] =
            *(const float4*)(adjs + (size_t)16 * N_ + j0);
        *(float4*)&lds_msk[srow * APAD_ + sf4] = *(const float4*)(msks + j0);
        *(float4*)&lds_msk[(srow + 16) * APAD_ + sf4] =
            *(const float4*)(msks + (size_t)16 * N_ + j0);
        lds_t[th * JST_ + tj] = tbs[j0];
        __syncthreads();
#pragma unroll
        for (int kc = 0; kc < KCS_; ++kc) {
            int jt = kc * 32 + quad * 8;               // col within stage
            int jl = j0 + kc * 32;                     // featsT idx (quad*8 in ptr)
            float4 t0 = *(const float4*)&lds_t[h * JST_ + jt];    // broadcast
            float4 t1 = *(const float4*)&lds_t[h * JST_ + jt + 4];
            short8v bv0 = *(const short8v*)(ft0 + jl);
            short8v bv1 = *(const short8v*)(ft1 + jl);
            float tv[8] = {t0.x, t0.y, t0.z, t0.w, t1.x, t1.y, t1.z, t1.w};
            PkU ap0, ap1;
            {   // rows r (rr=0)
                float4 a0 = *(const float4*)&lds_adj[r * APAD_ + jt];
                float4 a1 = *(const float4*)&lds_adj[r * APAD_ + jt + 4];
                float4 m0 = *(const float4*)&lds_msk[r * APAD_ + jt];
                float4 m1 = *(const float4*)&lds_msk[r * APAD_ + jt + 4];
                float av[8] = {a0.x,a0.y,a0.z,a0.w,a1.x,a1.y,a1.z,a1.w};
                float mv[8] = {m0.x,m0.y,m0.z,m0.w,m1.x,m1.y,m1.z,m1.w};
                attn_qstep(si0, av, mv, tv, l0, A0, ap0.i);
            }
            {   // rows r+16 (rr=1)
                float4 a0 = *(const float4*)&lds_adj[(r + 16) * APAD_ + jt];
                float4 a1 = *(const float4*)&lds_adj[(r + 16) * APAD_ + jt + 4];
                float4 m0 = *(const float4*)&lds_msk[(r + 16) * APAD_ + jt];
                float4 m1 = *(const float4*)&lds_msk[(r + 16) * APAD_ + jt + 4];
                float av[8] = {a0.x,a0.y,a0.z,a0.w,a1.x,a1.y,a1.z,a1.w};
                float mv[8] = {m0.x,m0.y,m0.z,m0.w,m1.x,m1.y,m1.z,m1.w};
                attn_qstep(si1, av, mv, tv, l1, A1, ap1.i);
            }
            acc00 = __builtin_amdgcn_mfma_f32_16x16x32_bf16(ap0.s, bv0, acc00, 0, 0, 0);
            acc01 = __builtin_amdgcn_mfma_f32_16x16x32_bf16(ap0.s, bv1, acc01, 0, 0, 0);
            acc10 = __builtin_amdgcn_mfma_f32_16x16x32_bf16(ap1.s, bv0, acc10, 0, 0, 0);
            acc11 = __builtin_amdgcn_mfma_f32_16x16x32_bf16(ap1.s, bv1, acc11, 0, 0, 0);
        }
    }
    // fold 4 k-group lanes -> row totals in lanes 0-15
    l0 += __shfl_down(l0, 32); l0 += __shfl_down(l0, 16);
    l1 += __shfl_down(l1, 32); l1 += __shfl_down(l1, 16);
    A0 += __shfl_down(A0, 32); A0 += __shfl_down(A0, 16);
    A1 += __shfl_down(A1, 32); A1 += __shfl_down(A1, 16);

    size_t pb = (((size_t)(b * H_ + h) * ITILES_ + it) * JCA_ + jc) * 1024;
    *(f32x4*)&part[pb + lane * 4]       = acc00;   // raw C-frags, coalesced
    *(f32x4*)&part[pb + 256 + lane * 4] = acc01;
    *(f32x4*)&part[pb + 512 + lane * 4] = acc10;
    *(f32x4*)&part[pb + 768 + lane * 4] = acc11;
    if (lane < 16) {
        size_t lb = (((size_t)(b * H_ + h) * ITILES_ + it) * JCA_ + jc) * 64;
        lpart[lb + lane]      = l0;      // rows 0-15
        lpart[lb + 16 + lane] = l1;      // rows 16-31
        lpart[lb + 32 + lane] = A0;
        lpart[lb + 48 + lane] = A1;
    }
}

// ---------------------------------------------------------------- kernel 3
// Block = (b, 32-row i-tile). Merge jc partials, /l, bias, BN, ReLU,
// LDS transpose, coalesced out; per-(block,h) eloss partial.
__global__ __launch_bounds__(256) void final_kernel(
    const float* __restrict__ part, const float* __restrict__ lpart,
    const float* __restrict__ bias, const float* __restrict__ gamma,
    const float* __restrict__ beta, const float* __restrict__ mmean,
    const float* __restrict__ mvar, float* __restrict__ lossbuf,
    float* __restrict__ out)
{
    __shared__ float ldsl[H_ * IT_];
    __shared__ float ldso[IT_ * 132];
    int blk = blockIdx.x;              // b*64 + it
    int b = blk >> 6, it = blk & 63;
    int t = threadIdx.x, h = t >> 6, lane = t & 63;
    int quad = lane >> 4, col = lane & 15;

    size_t pb = (((size_t)(b * H_ + h) * ITILES_ + it) * JCA_) * 1024;
    f32x4 C[4];
#pragma unroll
    for (int k = 0; k < 4; ++k) C[k] = (f32x4){0.f, 0.f, 0.f, 0.f};
#pragma unroll
    for (int c = 0; c < JCA_; ++c)
#pragma unroll
        for (int k = 0; k < 4; ++k)
            C[k] += *(const f32x4*)&part[pb + c * 1024 + k * 256 + lane * 4];

    size_t lb = (((size_t)(b * H_ + h) * ITILES_ + it) * JCA_) * 64;
    if (lane < 32) {
        float lt = 0.f, At = 0.f;
#pragma unroll
        for (int c = 0; c < JCA_; ++c) {
            lt += lpart[lb + c * 64 + lane];
            At += lpart[lb + c * 64 + 32 + lane];
        }
        ldsl[h * IT_ + lane] = lt;
        float e = At / lt;
#pragma unroll
        for (int off = 16; off; off >>= 1) e += __shfl_down(e, off);
        if (lane == 0) lossbuf[blk * H_ + h] = e;
    }
    __syncthreads();
#pragma unroll
    for (int dt = 0; dt < 2; ++dt) {
        int c = h * FP_ + dt * 16 + col;
        float sc = rsqrtf(mvar[c] + 1e-3f) * gamma[c];
        float sh = beta[c] - mmean[c] * sc;
        float bi = bias[c];
#pragma unroll
        for (int rr = 0; rr < 2; ++rr) {
            f32x4 Cv = C[rr * 2 + dt];
#pragma unroll
            for (int rrr = 0; rrr < 4; ++rrr) {
                int row = rr * 16 + quad * 4 + rrr;
                float node = Cv[rrr] / ldsl[h * IT_ + row] + bi;
                float o = node * sc + sh;
                ldso[row * 132 + c] = o > 0.f ? o : 0.f;
            }
        }
    }
    __syncthreads();
#pragma unroll
    for (int ps = 0; ps < 4; ++ps) {
        int s = ps * 256 + t;
        int row = s >> 5, c4 = (s & 31) * 4;
        *(float4*)(out + ((size_t)b * N_ + it * IT_ + row) * C_ + c4) =
            *(const float4*)&ldso[row * 132 + c4];
    }
}

// ---------------------------------------------------------------- kernel 4
__global__ __launch_bounds__(256) void loss_kernel(
    const float* __restrict__ lossbuf, float* __restrict__ out)
{
    float e = 0.f;
    for (int idx = threadIdx.x; idx < B_ * ITILES_ * H_; idx += 256)
        e += lossbuf[idx];
    __shared__ float se[256];
    se[threadIdx.x] = e;
    __syncthreads();
    for (int o = 128; o; o >>= 1) {
        if (threadIdx.x < o) se[threadIdx.x] += se[threadIdx.x + o];
        __syncthreads();
    }
    if (threadIdx.x == 0) {
        out[(size_t)B_ * N_ * C_]     = 0.f;                 // uloss == 0 exactly
        out[(size_t)B_ * N_ * C_ + 1] = se[0] * (1.f / N_);  // eloss
    }
}

// ---------------------------------------------------------------- launch
extern "C" void kernel_launch(void* const* d_in, const int* in_sizes, int n_in,
                              void* d_out, int out_size, void* d_ws, size_t ws_size,
                              hipStream_t stream)
{
    const float* x         = (const float*)d_in[0];
    const float* adj       = (const float*)d_in[1];
    const float* attn_mask = (const float*)d_in[2];
    const float* W         = (const float*)d_in[3];
    const float* a_self    = (const float*)d_in[4];
    const float* a_neigh   = (const float*)d_in[5];
    const float* bias      = (const float*)d_in[6];
    const float* gamma     = (const float*)d_in[7];
    const float* beta      = (const float*)d_in[8];
    const float* mmean     = (const float*)d_in[9];
    const float* mvar      = (const float*)d_in[10];
    float* out = (float*)d_out;

    float* ws = (float*)d_ws;
    unsigned short* featsT = (unsigned short*)ws;                      // 1,048,576 u16
    float* sbuf  = ws + 524288;                                        //    32,768 f
    float* tbuf  = sbuf + (size_t)B_ * H_ * N_;                        //    32,768 f
    float* part  = tbuf + (size_t)B_ * H_ * N_;                        // 8,388,608 f
    float* lpart = part + (size_t)B_ * H_ * ITILES_ * JCA_ * 1024;     //   524,288 f
    float* lossb = lpart + (size_t)B_ * H_ * ITILES_ * JCA_ * 64;      //     1,024 f

    hipLaunchKernelGGL(prep_kernel, dim3(B_ * 32), dim3(256), 0, stream,
                       x, W, a_self, a_neigh, featsT, sbuf, tbuf);
    hipLaunchKernelGGL(attn_kernel, dim3(B_ * ITILES_ * JCA_), dim3(256), 0, stream,
                       adj, attn_mask, featsT, sbuf, tbuf, part, lpart);
    hipLaunchKernelGGL(final_kernel, dim3(B_ * ITILES_), dim3(256), 0, stream,
                       part, lpart, bias, gamma, beta, mmean, mvar,
                       lossb, out);
    hipLaunchKernelGGL(loss_kernel, dim3(1), dim3(256), 0, stream,
                       lossb, out);
}